// Round 5
// baseline (2244.907 us; speedup 1.0000x reference)
//
#include <hip/hip_runtime.h>
#include <hip/hip_bf16.h>
#include <cstdint>
#include <cstddef>

#define NB 65536
#define DD 512
#define HH 1024

typedef __attribute__((ext_vector_type(8))) short short8;
typedef __attribute__((ext_vector_type(4))) short short4v;
typedef __attribute__((ext_vector_type(4))) float f32x4;

__device__ __forceinline__ float bf2f(short s){
  union { float f; unsigned u; } v; v.u = ((unsigned)(unsigned short)s) << 16; return v.f;
}
__device__ __forceinline__ short f2bf(float f){
  union { float f; unsigned u; } v; v.f = f;
  unsigned u = v.u;
  u += 0x7FFFu + ((u >> 16) & 1u);
  return (short)(u >> 16);
}
__device__ __forceinline__ float sigm(float x){ return 1.0f / (1.0f + __expf(-x)); }

// sum over the 16 lanes of a DPP row; result in all lanes
__device__ __forceinline__ float rowsum16(float v){
  int x;
  x = __builtin_amdgcn_update_dpp(0, __float_as_int(v), 0x128, 0xF, 0xF, true); v += __int_as_float(x); // ror:8
  x = __builtin_amdgcn_update_dpp(0, __float_as_int(v), 0x124, 0xF, 0xF, true); v += __int_as_float(x); // ror:4
  x = __builtin_amdgcn_update_dpp(0, __float_as_int(v), 0x122, 0xF, 0xF, true); v += __int_as_float(x); // ror:2
  x = __builtin_amdgcn_update_dpp(0, __float_as_int(v), 0x121, 0xF, 0xF, true); v += __int_as_float(x); // ror:1
  return v;
}

#define GLL(srcp, dstp) \
  __builtin_amdgcn_global_load_lds((const __attribute__((address_space(1))) void*)(srcp), \
                                   (__attribute__((address_space(3))) void*)(dstp), 16, 0, 0)

struct TileBB { const short* a; const short* b; int epi; };

#define ZERO_ACC8(acc) \
  _Pragma("unroll") for (int zi=0;zi<8;++zi) _Pragma("unroll") for (int zj=0;zj<4;++zj) \
    acc[zi][zj] = (f32x4){0.f,0.f,0.f,0.f};

#define LOADA(pb, a, s) { \
  const int ab_ = (s) ? aBase1 : aBase0; \
  _Pragma("unroll") for (int mi_=0;mi_<4;++mi_) \
    af[mi_] = *(const short8*)&smem[(pb) + ab_ + ((a)*4+mi_)*1024]; }

#define LOADB(pb, s) { \
  _Pragma("unroll") for (int nf_=0;nf_<4;++nf_) \
    bf[nf_] = *(const short8*)&smem[(pb) + bBase + (s)*8192 + nf_*512]; }

#define MFMA16(a) { \
  __builtin_amdgcn_s_setprio(1); \
  _Pragma("unroll") for (int mi_=0;mi_<4;++mi_) \
  _Pragma("unroll") for (int nf_=0;nf_<4;++nf_) \
    acc[(a)*4+mi_][nf_] = __builtin_amdgcn_mfma_f32_16x16x32_bf16(af[mi_], bf[nf_], acc[(a)*4+mi_][nf_], 0,0,0); \
  __builtin_amdgcn_s_setprio(0); }

#define BAR1() { __builtin_amdgcn_s_barrier(); \
  asm volatile("s_waitcnt lgkmcnt(0)" ::: "memory"); \
  __builtin_amdgcn_sched_barrier(0); }

#define VM8()  asm volatile("s_waitcnt vmcnt(8)" ::: "memory")
#define BAR2() __builtin_amdgcn_s_barrier()
#define FENCE() asm volatile("" ::: "memory")

// ============================================================================
// Persistent tile-streaming 256x256 NT GEMM (8-phase class, T2+T3+T4+T5).
// One block per CU streams NT tiles through ONE continuous pipeline: the
// flattened (tile, kt) loop preserves the per-phase op pattern exactly
// (2 GLL/wave/phase, vmcnt(8) counted, parity = kt&1 continues since NK=8
// even), staging tile t+1's first K-tiles during tile t's last phases.
// Pipeline drains only once at kernel end; per-tile epilogue overlaps the
// next tile's in-flight stages.  K-chunk fixed at 512 (NK=8).
// ============================================================================
template<int LDA, int LDB, int NT, class TileFn, class EpiFn>
__device__ __forceinline__ void gemm_stream(short* smem, TileFn tf, EpiFn ef)
{
  const int tid = threadIdx.x;
  const int wave = tid>>6, lane = tid&63;
  const int wm = wave>>2, wn = wave&3;
  const int lr = lane&15, lq = lane>>4;

  // ds_read bases (shorts)
  const int wmbase = wm*128 + lr;
  const int gA0 = (lq)     ^ (wmbase&7);
  const int gA1 = (4 + lq) ^ (wmbase&7);
  const int aBase0 = wmbase*64 + gA0*8;
  const int aBase1 = wmbase*64 + gA1*8;
  const int gB = ((lr&1)*4 + lq) ^ ((lr>>1)&7);
  const int bBase = 32768 + (wn*32 + (lr>>1))*64 + gB*8;

  // stage source addressing (per-lane)
  const int aRic = lane>>3;
  const int aCg  = (lane&7) ^ (aRic&7);
  const int bSric = lane>>3;
  const int bG    = (lane&7) ^ (bSric&7);
  const int bN    = 2*bSric + (bG>>2);
  const int bK    = (bG&3)*8;

  auto abase = [&](const short* A)->const short*{ return A + (size_t)aRic*LDA + aCg*8; };
  auto bbase = [&](const short* B)->const short*{ return B + (size_t)bN*LDB + bK; };

  auto stA = [&](const short* a, int kt2, int aa){
    const int p2 = (kt2&1)*16384;
#pragma unroll
    for (int i=0;i<2;++i){ int ci=wave*2+i; int c=aa*8+ci+(ci>=8?8:0);
      GLL(a + (size_t)c*8*LDA + kt2*64, smem + p2 + c*512); } };
  auto stB = [&](const short* b, int kt2, int h){
    const int p2 = (kt2&1)*16384;
#pragma unroll
    for (int i=0;i<2;++i){ int ci=wave*2+i;
      GLL(b + (size_t)ci*16*LDB + kt2*64 + h*32, smem + 32768 + p2 + h*8192 + ci*512); } };

  f32x4 acc[8][4]; ZERO_ACC8(acc);
  short8 af[4], bf[4];

  const short *aCur, *bCur, *aNx, *bNx; int epiCur;
  { TileBB t0 = tf(0);      aCur=abase(t0.a); bCur=bbase(t0.b); epiCur=t0.epi; }
  { TileBB t1 = tf(1%NT);   aNx =abase(t1.a); bNx =bbase(t1.b); }

  // prologue: kt0/kt1 of tile 0
  stB(bCur,0,0); stA(aCur,0,0); stA(aCur,0,1); stB(bCur,0,1); stB(bCur,1,0); stA(aCur,1,0);
  VM8(); BAR2();

  for (int t=0; t<NT; ++t){
#pragma unroll
    for (int kt=0; kt<8; ++kt){
      const int pb = (kt&1)*16384;
      const short* a1 = (kt+1<8)? aCur : aNx;  const short* b1 = (kt+1<8)? bCur : bNx;
      const short* a2 = (kt+2<8)? aCur : aNx;  const short* b2 = (kt+2<8)? bCur : bNx;
      const int k1 = (kt+1)&7, k2 = (kt+2)&7;
      // j0
      LOADA(pb,0,0); LOADB(pb,0); stA(a1,k1,1);
      BAR1(); MFMA16(0); VM8(); BAR2();
      // j1
      LOADA(pb,1,0); stB(b1,k1,1);
      BAR1(); MFMA16(1); VM8(); BAR2();
      // j2
      LOADA(pb,0,1); LOADB(pb,1); stB(b2,k2,0);
      BAR1(); MFMA16(0); FENCE(); BAR2();
      // j3
      LOADA(pb,1,1); stA(a2,k2,0);
      BAR1(); MFMA16(1); VM8(); BAR2();
    }
    if (epiCur){ ef(t, acc); ZERO_ACC8(acc); }
    aCur = aNx; bCur = bNx;
    { TileBB tn = tf((t+1)%NT); epiCur = tn.epi; }
    { TileBB t2 = tf((t+2)%NT); aNx = abase(t2.a); bNx = bbase(t2.b); }
  }
  asm volatile("s_waitcnt vmcnt(0)" ::: "memory");
}

// ---- CMS level GEMM1: H = relu(out @ w1^T + b1), bf16 out. per-CU m-panel, 4 n-tiles
__global__ __launch_bounds__(512, 2) void k_gemm_h(const int* __restrict__ gs, int freq,
     const short* __restrict__ A, const short* __restrict__ W1, const float* __restrict__ b1,
     short* __restrict__ Hout)
{
  if (gs[0] % freq) return;
  __shared__ __align__(16) short smem[65536];
  const int tid = threadIdx.x, wave = tid>>6, lane = tid&63;
  const int wm = wave>>2, wn = wave&3, lr = lane&15, lq = lane>>4;
  const int m0 = blockIdx.x*256;
  auto tf = [&](int t)->TileBB{
    return TileBB{ A + (size_t)m0*DD, W1 + (size_t)t*256*DD, 1 };
  };
  auto ef = [&](int t, f32x4 (&acc)[8][4]){
    const int n0 = t*256;
    const int rb = m0 + wm*128 + lq*4;
    const int cb = n0 + wn*64 + lr;
#pragma unroll
    for (int nf=0;nf<4;++nf){
      const float bias = b1[cb + nf*16];
#pragma unroll
      for (int mf=0;mf<8;++mf)
#pragma unroll
        for (int rr=0;rr<4;++rr){
          float v = acc[mf][nf][rr] + bias;
          v = v > 0.f ? v : 0.f;
          Hout[(size_t)(rb + mf*16 + rr)*HH + (cb + nf*16)] = f2bf(v);
        }
    }
  };
  gemm_stream<DD, DD, 4>(smem, tf, ef);
}

// ---- CMS level GEMM2: out += H @ w2^T + b2. per-CU m-panel, 2 n-tiles x 2 k-halves
__global__ __launch_bounds__(512, 2) void k_gemm_res(const int* __restrict__ gs, int freq,
     const short* __restrict__ Hb, const short* __restrict__ W2, const float* __restrict__ b2,
     float* __restrict__ outf, short* __restrict__ outb)
{
  if (gs[0] % freq) return;
  __shared__ __align__(16) short smem[65536];
  const int tid = threadIdx.x, wave = tid>>6, lane = tid&63;
  const int wm = wave>>2, wn = wave&3, lr = lane&15, lq = lane>>4;
  const int m0 = blockIdx.x*256;
  auto tf = [&](int t)->TileBB{
    const int nb = t>>1, kh = t&1;
    return TileBB{ Hb + (size_t)m0*HH + kh*512,
                   W2 + (size_t)nb*256*HH + kh*512, kh };
  };
  auto ef = [&](int t, f32x4 (&acc)[8][4]){
    const int n0 = (t>>1)*256;
    const int rb = m0 + wm*128 + lq*4;
    const int cb = n0 + wn*64 + lr;
#pragma unroll
    for (int nf=0;nf<4;++nf){
      const float bias = b2[cb + nf*16];
#pragma unroll
      for (int mf=0;mf<8;++mf)
#pragma unroll
        for (int rr=0;rr<4;++rr){
          size_t off = (size_t)(rb + mf*16 + rr)*DD + (cb + nf*16);
          float v = acc[mf][nf][rr] + bias + outf[off];
          outf[off] = v;
          outb[off] = f2bf(v);
        }
    }
  };
  gemm_stream<HH, HH, 4>(smem, tf, ef);
}

// ---- gates fused with gate-out: per-CU m-panel, 12 (j,n) tiles; per-row dot
// with the 3 g_out_w rows, banked LDS reduce, non-atomic partial store.
__global__ __launch_bounds__(512, 2) void k_gates(const short* __restrict__ A, const short* __restrict__ WG,
     const float* __restrict__ bm, const float* __restrict__ bs, const float* __restrict__ bg,
     const float* __restrict__ gow, float* __restrict__ pacc)
{
  __shared__ __align__(16) short smem[65536];
  __shared__ float sredb[4][256][3];
  const int tid = threadIdx.x, wave = tid>>6, lane = tid&63;
  const int wm = wave>>2, wn = wave&3, lr = lane&15, lq = lane>>4;
  const int m0 = blockIdx.x*256;
  auto tf = [&](int t)->TileBB{
    const int j = t>>2, nb = t&3;
    return TileBB{ A + (size_t)m0*DD,
                   WG + (size_t)j*HH*DD + (size_t)nb*256*DD, 1 };
  };
  auto ef = [&](int t, f32x4 (&acc)[8][4]){
    const int j = t>>2, nb = t&3;
    const int n0 = nb*256;
    const int cb = n0 + wn*64 + lr;
    const float* bj = (j==0) ? bm : ((j==1) ? bs : bg);
    float gw0[4], gw1[4], gw2[4], bias[4];
#pragma unroll
    for (int nf=0;nf<4;++nf){
      gw0[nf]  = gow[cb + nf*16];
      gw1[nf]  = gow[1024 + cb + nf*16];
      gw2[nf]  = gow[2048 + cb + nf*16];
      bias[nf] = bj[cb + nf*16];
    }
    __syncthreads();   // previous epilogue's readers done with sredb
#pragma unroll
    for (int mf=0;mf<8;++mf)
#pragma unroll
      for (int rr=0;rr<4;++rr){
        float s0=0.f, s1=0.f, s2=0.f;
#pragma unroll
        for (int nf=0;nf<4;++nf){
          float v = sigm(acc[mf][nf][rr] + bias[nf]);
          s0 += v*gw0[nf]; s1 += v*gw1[nf]; s2 += v*gw2[nf];
        }
        s0 = rowsum16(s0); s1 = rowsum16(s1); s2 = rowsum16(s2);
        if (lr == 0){
          int lrow = wm*128 + mf*16 + lq*4 + rr;
          sredb[wn][lrow][0] = s0;
          sredb[wn][lrow][1] = s1;
          sredb[wn][lrow][2] = s2;
        }
      }
    __syncthreads();
    if (tid < 256){
      float a0 = sredb[0][tid][0]+sredb[1][tid][0]+sredb[2][tid][0]+sredb[3][tid][0];
      float a1 = sredb[0][tid][1]+sredb[1][tid][1]+sredb[2][tid][1]+sredb[3][tid][1];
      float a2 = sredb[0][tid][2]+sredb[1][tid][2]+sredb[2][tid][2]+sredb[3][tid][2];
      float* dst = &pacc[((size_t)t*NB + m0 + tid)*3];
      dst[0]=a0; dst[1]=a1; dst[2]=a2;
    }
  };
  gemm_stream<DD, DD, 12>(smem, tf, ef);
}

// ---- slow/fast as one N=1024 GEMM over WSF=[W_slow;W_fast]; 4 n-tiles
__global__ __launch_bounds__(512, 2) void k_slowfast(const short* __restrict__ A,
     const short* __restrict__ WSF,
     short* __restrict__ SB, short* __restrict__ FB, float* __restrict__ f2sum)
{
  __shared__ __align__(16) short smem[65536];
  __shared__ float f2red[256];
  const int tid = threadIdx.x, wave = tid>>6, lane = tid&63;
  const int wm = wave>>2, wn = wave&3, lr = lane&15, lq = lane>>4;
  const int m0 = blockIdx.x*256;
  auto tf = [&](int t)->TileBB{
    return TileBB{ A + (size_t)m0*DD, WSF + (size_t)t*256*DD, 1 };
  };
  auto ef = [&](int t, f32x4 (&acc)[8][4]){
    const int n0 = t*256;
    const int rb = m0 + wm*128 + lq*4;
    const int cb = n0 + wn*64 + lr;
    if (t < 2){
#pragma unroll
      for (int nf=0;nf<4;++nf)
#pragma unroll
        for (int mf=0;mf<8;++mf)
#pragma unroll
          for (int rr=0;rr<4;++rr)
            SB[(size_t)(rb + mf*16 + rr)*DD + (cb + nf*16)] = f2bf(acc[mf][nf][rr]);
    } else {
      __syncthreads();
      if (tid < 256) f2red[tid] = 0.f;
      __syncthreads();
#pragma unroll
      for (int nf=0;nf<4;++nf){
        float p = 0.f;
        const int fcol = cb + nf*16 - 512;
#pragma unroll
        for (int mf=0;mf<8;++mf)
#pragma unroll
          for (int rr=0;rr<4;++rr){
            float fv = acc[mf][nf][rr];
            FB[(size_t)(rb + mf*16 + rr)*DD + fcol] = f2bf(fv);
            p += fv*fv;
          }
        atomicAdd(&f2red[(wn*64 + nf*16 + lr)], p);
      }
      __syncthreads();
      if (tid < 256) atomicAdd(&f2sum[(n0-512) + tid], f2red[tid]);
    }
  };
  gemm_stream<DD, DD, 4>(smem, tf, ef);
}

// ---- hebb = fast^T @ x_cms (TN GEMM via LDS transpose, split-K=16 over B)
__global__ __launch_bounds__(256) void k_hebb(const short* __restrict__ FB,
     const short* __restrict__ XB, float* __restrict__ hebb)
{
  __shared__ __align__(16) short sT[10240];
  const int tid = threadIdx.x, wave = tid>>6, lane = tid&63;
  const int o0 = blockIdx.x*128, d0 = blockIdx.y*128;
  const int bz = blockIdx.z;
  const int tr = tid>>3;
  const int tc = (tid&7)*16;
  const int wm=(wave>>1)*64, wn=(wave&1)*64;
  const int lr = lane & 15, lk = (lane>>4)*8;
  f32x4 acc[4][4];
#pragma unroll
  for (int zi=0;zi<4;++zi)
#pragma unroll
    for (int zj=0;zj<4;++zj) acc[zi][zj] = (f32x4){0.f,0.f,0.f,0.f};
  for (int bb=0; bb<4096; bb+=32){
    const int b0 = bz*4096 + bb;
    __syncthreads();
#pragma unroll
    for (int h=0; h<2; ++h){
      short8 v = *(const short8*)&FB[(size_t)(b0+tr)*DD + o0 + tc + h*8];
#pragma unroll
      for (int j=0;j<8;++j) sT[(tc+h*8+j)*40 + tr] = v[j];
      short8 u = *(const short8*)&XB[(size_t)(b0+tr)*DD + d0 + tc + h*8];
#pragma unroll
      for (int j=0;j<8;++j) sT[5120 + (tc+h*8+j)*40 + tr] = u[j];
    }
    __syncthreads();
    short8 af[4], bf[4];
#pragma unroll
    for (int i=0;i<4;++i) af[i] = *(const short8*)&sT[(wm + i*16 + lr)*40 + lk];
#pragma unroll
    for (int i=0;i<4;++i) bf[i] = *(const short8*)&sT[5120 + (wn + i*16 + lr)*40 + lk];
#pragma unroll
    for (int mi=0;mi<4;++mi)
#pragma unroll
      for (int ni=0;ni<4;++ni)
        acc[mi][ni] = __builtin_amdgcn_mfma_f32_16x16x32_bf16(af[mi], bf[ni], acc[mi][ni], 0,0,0);
  }
  const int rbase = o0 + wm + ((lane>>4)<<2);
  const int cbase = d0 + wn + (lane&15);
#pragma unroll
  for (int mi=0;mi<4;++mi)
#pragma unroll
    for (int ni=0;ni<4;++ni)
#pragma unroll
      for (int r=0;r<4;++r)
        atomicAdd(&hebb[(size_t)(rbase + mi*16 + r)*DD + (cbase + ni*16)], acc[mi][ni][r]);
}

// ---- finalize gates: sum 12 partial slices, sigmoid, stats
__global__ __launch_bounds__(256) void k_gatefin(const float* __restrict__ pacc,
     const float* __restrict__ gob,
     float* __restrict__ sensb, float* __restrict__ gateb, float* __restrict__ sacc)
{
  __shared__ float red[3][256];
  const int tid = threadIdx.x;
  const int row = blockIdx.x*256 + tid;
  float a0=0.f, a1=0.f, a2=0.f;
#pragma unroll
  for (int sidx=0; sidx<12; ++sidx){
    const float* p = &pacc[((size_t)sidx*NB + row)*3];
    a0 += p[0]; a1 += p[1]; a2 += p[2];
  }
  float m = sigm(a0 + gob[0]);
  float s = sigm(a1 + gob[1]);
  float g = sigm(a2 + gob[2]);
  sensb[row] = s; gateb[row] = g;
  red[0][tid]=m; red[1][tid]=s; red[2][tid]=g;
  __syncthreads();
  for (int off=128; off; off>>=1){
    if (tid < off){
      red[0][tid]+=red[0][tid+off];
      red[1][tid]+=red[1][tid+off];
      red[2][tid]+=red[2][tid+off];
    }
    __syncthreads();
  }
  if (tid < 3) atomicAdd(&sacc[tid], red[tid][0]);
}

// ---- combined/SiLU-beta/LayerNorm epilogue: one wave per row
__global__ __launch_bounds__(256) void k_ln(const short* __restrict__ SB, const short* __restrict__ FB,
     const float* __restrict__ gate, const float* __restrict__ sens,
     const float* __restrict__ gam, const float* __restrict__ bet, float* __restrict__ out)
{
  const int tid = threadIdx.x, wave = tid>>6, lane = tid&63;
  const int row = blockIdx.x*4 + wave;
  const float g = gate[row], s = sens[row];
  const float bcoef = 0.5f + 2.0f*s;
  const int c0 = lane*8;
  short8 sv = *(const short8*)&SB[(size_t)row*DD + c0];
  short8 fv = *(const short8*)&FB[(size_t)row*DD + c0];
  float a[8]; float sum = 0.f;
#pragma unroll
  for (int j=0;j<8;++j){
    float c = bf2f(sv[j]) + bf2f(fv[j])*g;
    float av = c * sigm(bcoef*c);
    a[j] = av; sum += av;
  }
  for (int off=32; off; off>>=1) sum += __shfl_down(sum, off);
  sum = __shfl(sum, 0);
  const float mu = sum * (1.f/512.f);
  float vs = 0.f;
#pragma unroll
  for (int j=0;j<8;++j){ float d=a[j]-mu; vs += d*d; }
  for (int off=32; off; off>>=1) vs += __shfl_down(vs, off);
  vs = __shfl(vs, 0);
  const float rstd = rsqrtf(vs*(1.f/512.f) + 1e-5f);
  f32x4 o0, o1;
#pragma unroll
  for (int j=0;j<4;++j) o0[j] = (a[j]-mu)*rstd*gam[c0+j] + bet[c0+j];
#pragma unroll
  for (int j=0;j<4;++j) o1[j] = (a[4+j]-mu)*rstd*gam[c0+4+j] + bet[c0+4+j];
  *(f32x4*)&out[(size_t)row*DD + c0]     = o0;
  *(f32x4*)&out[(size_t)row*DD + c0 + 4] = o1;
}

// ---- new_W_fast + stats
__global__ __launch_bounds__(256) void k_wfast(const float* __restrict__ hebb,
     const float* __restrict__ f2sum, const float* __restrict__ sacc,
     const float* __restrict__ Wf, float* __restrict__ outw, float* __restrict__ outstats)
{
  const int idx = blockIdx.x*256 + threadIdx.x;
  if (idx >= 262144) return;
  const float inv = 1.f/65536.f;
  const float rate = sacc[0] * inv * 0.1f;
  const int o = idx >> 9;
  float w = Wf[idx];
  float h = hebb[idx] * inv;
  float forget = f2sum[o] * inv * w;
  outw[idx] = w + tanhf(h - forget) * rate;
  if (idx < 3) outstats[idx] = sacc[idx] * inv;
}

// ---- casts
__global__ __launch_bounds__(256) void k_castw(const float* __restrict__ src, short* __restrict__ dst, int n)
{
  int i = blockIdx.x*256 + threadIdx.x;
  if (i < n) dst[i] = f2bf(src[i]);
}
__global__ __launch_bounds__(256) void k_castx(const float* __restrict__ x,
     float* __restrict__ outf, short* __restrict__ outb)
{
  int i = blockIdx.x*256 + threadIdx.x;
  f32x4 v = *(const f32x4*)&x[(size_t)i*4];
  *(f32x4*)&outf[(size_t)i*4] = v;
  short4v b;
#pragma unroll
  for (int j=0;j<4;++j) b[j] = f2bf(v[j]);
  *(short4v*)&outb[(size_t)i*4] = b;
}

extern "C" void kernel_launch(void* const* d_in, const int* in_sizes, int n_in,
                              void* d_out, int out_size, void* d_ws, size_t ws_size,
                              hipStream_t stream)
{
  const float* x    = (const float*)d_in[0];
  const int*   gs   = (const int*)d_in[1];
  const float* w1   = (const float*)d_in[2];
  const float* b1   = (const float*)d_in[3];
  const float* w2   = (const float*)d_in[4];
  const float* b2   = (const float*)d_in[5];
  const float* gmw  = (const float*)d_in[6];
  const float* gmb  = (const float*)d_in[7];
  const float* gsw  = (const float*)d_in[8];
  const float* gsb  = (const float*)d_in[9];
  const float* ggw  = (const float*)d_in[10];
  const float* ggb  = (const float*)d_in[11];
  const float* gow  = (const float*)d_in[12];
  const float* gob  = (const float*)d_in[13];
  const float* wslow= (const float*)d_in[14];
  const float* wfast= (const float*)d_in[15];
  const float* gam  = (const float*)d_in[16];
  const float* bet  = (const float*)d_in[17];

  char* ws = (char*)d_ws;
  float* outf  = (float*)(ws + 0);            // fp32 x_cms master (dead after CMS)
  short* outb  = (short*)(ws + 134217728);    // x_cms bf16
  short* hbuf  = (short*)(ws + 201326592);    // H bf16 (CMS); pacc overlays later
  short* wcW1  = (short*)(ws + 335544320);
  short* wcW2  = (short*)(ws + 338690048);
  short* wcG   = (short*)(ws + 341835776);
  short* wcWSF = (short*)(ws + 344981504);    // [W_slow;W_fast] = [1024][512] bf16
  float* hebb  = (float*)(ws + 346030080);
  float* f2sum = (float*)(ws + 347078656);
  float* sacc  = (float*)(ws + 347080704);
  float* sensb = (float*)(ws + 347080960);
  float* gateb = (float*)(ws + 347343104);
  float* pacc  = (float*)(ws + 201326592);    // overlays hbuf (dead after CMS)
  short* slowb = (short*)(ws + 0);            // overlays outf (dead after CMS)
  short* fastb = (short*)(ws + 67108864);

  float* o_ln = (float*)d_out;
  float* o_wf = o_ln + (size_t)NB*DD;
  float* o_st = o_wf + 262144;

  hipMemsetAsync(hebb, 0, 1048576, stream);
  hipMemsetAsync(f2sum, 0, 2048, stream);
  hipMemsetAsync(sacc, 0, 256, stream);

  k_castw<<<dim3(6144),256,0,stream>>>(w1, wcW1, 1572864);
  k_castw<<<dim3(6144),256,0,stream>>>(w2, wcW2, 1572864);
  k_castw<<<dim3(2048),256,0,stream>>>(gmw, wcG, 524288);
  k_castw<<<dim3(2048),256,0,stream>>>(gsw, wcG + 524288, 524288);
  k_castw<<<dim3(2048),256,0,stream>>>(ggw, wcG + 1048576, 524288);
  k_castw<<<dim3(1024),256,0,stream>>>(wslow, wcWSF, 262144);
  k_castw<<<dim3(1024),256,0,stream>>>(wfast, wcWSF + 262144, 262144);
  k_castx<<<dim3(32768),256,0,stream>>>(x, outf, outb);

  const int freqs[3] = {1,4,16};
  for (int lv=0; lv<3; ++lv){
    k_gemm_h  <<<dim3(256),512,0,stream>>>(gs, freqs[lv], outb, wcW1 + (size_t)lv*524288, b1 + lv*HH, hbuf);
    k_gemm_res<<<dim3(256),512,0,stream>>>(gs, freqs[lv], hbuf, wcW2 + (size_t)lv*524288, b2 + lv*DD, outf, outb);
  }

  k_gates   <<<dim3(256),512,0,stream>>>(outb, wcG, gmb, gsb, ggb, gow, pacc);
  k_gatefin <<<dim3(256),256,0,stream>>>(pacc, gob, sensb, gateb, sacc);
  k_slowfast<<<dim3(256),512,0,stream>>>(outb, wcWSF, slowb, fastb, f2sum);
  k_hebb    <<<dim3(4,4,16),256,0,stream>>>(fastb, outb, hebb);
  k_ln      <<<dim3(16384),256,0,stream>>>(slowb, fastb, gateb, sensb, gam, bet, o_ln);
  k_wfast   <<<dim3(1024),256,0,stream>>>(hebb, f2sum, sacc, wfast, o_wf, o_st);
}

// Round 6
// 1789.446 us; speedup vs baseline: 1.2545x; 1.2545x over previous
//
#include <hip/hip_runtime.h>
#include <hip/hip_bf16.h>
#include <cstdint>
#include <cstddef>

#define NB 65536
#define DD 512
#define HH 1024

typedef __attribute__((ext_vector_type(8))) short short8;
typedef __attribute__((ext_vector_type(4))) short short4v;
typedef __attribute__((ext_vector_type(4))) float f32x4;

__device__ __forceinline__ float bf2f(short s){
  union { float f; unsigned u; } v; v.u = ((unsigned)(unsigned short)s) << 16; return v.f;
}
__device__ __forceinline__ short f2bf(float f){
  union { float f; unsigned u; } v; v.f = f;
  unsigned u = v.u;
  u += 0x7FFFu + ((u >> 16) & 1u);
  return (short)(u >> 16);
}
__device__ __forceinline__ float sigm(float x){ return 1.0f / (1.0f + __expf(-x)); }

// sum over the 16 lanes of a DPP row; result in all lanes
__device__ __forceinline__ float rowsum16(float v){
  int x;
  x = __builtin_amdgcn_update_dpp(0, __float_as_int(v), 0x128, 0xF, 0xF, true); v += __int_as_float(x); // ror:8
  x = __builtin_amdgcn_update_dpp(0, __float_as_int(v), 0x124, 0xF, 0xF, true); v += __int_as_float(x); // ror:4
  x = __builtin_amdgcn_update_dpp(0, __float_as_int(v), 0x122, 0xF, 0xF, true); v += __int_as_float(x); // ror:2
  x = __builtin_amdgcn_update_dpp(0, __float_as_int(v), 0x121, 0xF, 0xF, true); v += __int_as_float(x); // ror:1
  return v;
}

// XCD-bijective remap: each XCD gets a contiguous m-range; the NX (n/j)-blocks
// sharing one A-tile run consecutively on the same XCD -> A-tile L2 reuse.
__device__ __forceinline__ int2 xcd_remap(int NX, int G){
  int flat = blockIdx.y*NX + blockIdx.x;
  int l = (flat & 7)*(G>>3) + (flat>>3);
  return make_int2(l / NX, l % NX);   // (m-tile, xj)
}

#define GLL(srcp, dstp) \
  __builtin_amdgcn_global_load_lds((const __attribute__((address_space(1))) void*)(srcp), \
                                   (__attribute__((address_space(3))) void*)(dstp), 16, 0, 0)

// ============================================================================
// 256x256-tile NT GEMM core, MERGED 2-phase schedule (T2+T3+T4+T5).
// C[m,n] = sum_k A[m,k]*W[n,k], A:[M][K], W:[N][K] bf16 row-major.
// 512 threads = 8 waves (2M x 4N), per-wave 128x64 output, acc[8][4].
// LDS 128 KiB: A: 2buf x [256 rows][64 cols] XOR-swizzled 16B granules;
//              B: 2buf x [2 khalf][128 superrow(=2 n-rows)][64] swizzled.
// Per K-tile 2 phases of 32 MFMA each (halves barrier tax vs 4-phase):
//  J01(kt): ds_read A(a0,s0)+A(a1,s0)+B(h0); stage ALL 4 units of kt+1
//           (opposite parity -> no same-phase read/write conflict);
//           barrier; lgkmcnt(0); 32 MFMA; vmcnt(8); barrier.
//  J23(kt): ds_read A(a0,s1)+A(a1,s1)+B(h1); barrier; lgkmcnt(0); 32 MFMA;
//           vmcnt(2)  [forces A0,B0,A1 of kt+1 resident; B1(kt+1) stays in
//           flight, drained by J01(kt+1)'s vmcnt(8)]; barrier.
// Only the peeled last K-tile drains vmcnt to 0.
// ============================================================================
template<int KTOT>
__device__ __forceinline__ void gemm256(const short* __restrict__ A, const short* __restrict__ W,
        int m0, int n0, short* smem, f32x4 acc[8][4])
{
  constexpr int NK = KTOT/64;
  static_assert(NK >= 4 && (NK & 1) == 0, "NK");
  const int tid = threadIdx.x;
  const int wave = tid>>6, lane = tid&63;
  const int wm = wave>>2, wn = wave&3;
  const int lr = lane&15, lq = lane>>4;

  // ---- ds_read bases (shorts)
  const int wmbase = wm*128 + lr;
  const int gA0 = (lq)     ^ (wmbase&7);
  const int gA1 = (4 + lq) ^ (wmbase&7);
  const int aBase0 = wmbase*64 + gA0*8;          // + p*16384 + (a*4+mi)*1024
  const int aBase1 = wmbase*64 + gA1*8;
  const int gB = ((lr&1)*4 + lq) ^ ((lr>>1)&7);
  const int bBase = 32768 + (wn*32 + (lr>>1))*64 + gB*8;  // + p*16384 + s*8192 + nf*512

  // ---- stage source addressing (per-lane, inverse-swizzled)
  const int aRic = lane>>3;
  const int aCg  = (lane&7) ^ (aRic&7);
  const int bSric = lane>>3;
  const int bG    = (lane&7) ^ (bSric&7);
  const int bN    = 2*bSric + (bG>>2);
  const int bK    = (bG&3)*8;

  const short* aSrc = A + (size_t)(m0 + aRic)*KTOT + aCg*8;
  const short* bSrc = W + (size_t)(n0 + bN)*KTOT + bK;

#define STAGEA(kt2, a) { \
  const int p2_ = ((kt2)&1)*16384; \
  _Pragma("unroll") for (int i_=0;i_<2;++i_){ \
    int ci_ = wave*2 + i_; \
    int c_  = (a)*8 + ci_ + (ci_>=8 ? 8 : 0); \
    GLL(aSrc + (size_t)c_*8*KTOT + (kt2)*64, smem + p2_ + c_*512); } }

#define STAGEB(kt2, h) { \
  const int p2_ = ((kt2)&1)*16384; \
  _Pragma("unroll") for (int i_=0;i_<2;++i_){ \
    int ci_ = wave*2 + i_; \
    GLL(bSrc + (size_t)ci_*16*KTOT + (kt2)*64 + (h)*32, smem + 32768 + p2_ + (h)*8192 + ci_*512); } }

#define LOADAR(R, pb, a, s) { \
  const int ab_ = (s) ? aBase1 : aBase0; \
  _Pragma("unroll") for (int mi_=0;mi_<4;++mi_) \
    R[mi_] = *(const short8*)&smem[(pb) + ab_ + ((a)*4+mi_)*1024]; }

#define LOADB(pb, s) { \
  _Pragma("unroll") for (int nf_=0;nf_<4;++nf_) \
    bf[nf_] = *(const short8*)&smem[(pb) + bBase + (s)*8192 + nf_*512]; }

#define MFMA16R(R, a) { \
  _Pragma("unroll") for (int mi_=0;mi_<4;++mi_) \
  _Pragma("unroll") for (int nf_=0;nf_<4;++nf_) \
    acc[(a)*4+mi_][nf_] = __builtin_amdgcn_mfma_f32_16x16x32_bf16(R[mi_], bf[nf_], acc[(a)*4+mi_][nf_], 0,0,0); }

#define BAR1() { __builtin_amdgcn_s_barrier(); \
  asm volatile("s_waitcnt lgkmcnt(0)" ::: "memory"); \
  __builtin_amdgcn_sched_barrier(0); }

#define BAR2() __builtin_amdgcn_s_barrier()
#define VMW(n) asm volatile("s_waitcnt vmcnt(" #n ")" ::: "memory")

  short8 af[4], ag[4], bf[4];

  // prologue: stage all 4 units of kt=0; leave B1(0) in flight (drained at
  // J01(0)'s vmcnt(8) before J23(0) reads it).
  STAGEA(0,0); STAGEB(0,0); STAGEA(0,1); STAGEB(0,1);
  VMW(2); BAR2();

#pragma unroll 2
  for (int kt = 0; kt < NK-1; ++kt){
    const int pb = (kt&1)*16384;
    // J01
    LOADAR(af, pb, 0, 0); LOADAR(ag, pb, 1, 0); LOADB(pb, 0);
    STAGEA(kt+1,0); STAGEB(kt+1,0); STAGEA(kt+1,1); STAGEB(kt+1,1);
    BAR1();
    __builtin_amdgcn_s_setprio(1);
    MFMA16R(af, 0); MFMA16R(ag, 1);
    __builtin_amdgcn_s_setprio(0);
    VMW(8); BAR2();
    // J23
    LOADAR(af, pb, 0, 1); LOADAR(ag, pb, 1, 1); LOADB(pb, 1);
    BAR1();
    __builtin_amdgcn_s_setprio(1);
    MFMA16R(af, 0); MFMA16R(ag, 1);
    __builtin_amdgcn_s_setprio(0);
    VMW(2); BAR2();
  }
  { // peeled kt = NK-1 (no stages; drain)
    const int pb = ((NK-1)&1)*16384;
    LOADAR(af, pb, 0, 0); LOADAR(ag, pb, 1, 0); LOADB(pb, 0);
    BAR1();
    __builtin_amdgcn_s_setprio(1);
    MFMA16R(af, 0); MFMA16R(ag, 1);
    __builtin_amdgcn_s_setprio(0);
    VMW(0); BAR2();
    LOADAR(af, pb, 0, 1); LOADAR(ag, pb, 1, 1); LOADB(pb, 1);
    BAR1();
    __builtin_amdgcn_s_setprio(1);
    MFMA16R(af, 0); MFMA16R(ag, 1);
    __builtin_amdgcn_s_setprio(0);
    BAR2();
  }
#undef STAGEA
#undef STAGEB
#undef LOADAR
#undef LOADB
#undef MFMA16R
#undef BAR1
#undef BAR2
#undef VMW
}

#define ZERO_ACC8(acc) \
  _Pragma("unroll") for (int zi=0;zi<8;++zi) _Pragma("unroll") for (int zj=0;zj<4;++zj) \
    acc[zi][zj] = (f32x4){0.f,0.f,0.f,0.f};

// ---- CMS level GEMM1: H = relu(out @ w1^T + b1), bf16 out. N=1024, K=512
__global__ __launch_bounds__(512, 2) void k_gemm_h(const int* __restrict__ gs, int freq,
     const short* __restrict__ A, const short* __restrict__ W1, const float* __restrict__ b1,
     short* __restrict__ Hout)
{
  if (gs[0] % freq) return;
  __shared__ __align__(16) short smem[65536];
  const int tid = threadIdx.x, wave = tid>>6, lane = tid&63;
  const int wm = wave>>2, wn = wave&3, lr = lane&15, lq = lane>>4;
  int2 r = xcd_remap(4, 1024);
  const int m0 = r.x*256, n0 = r.y*256;
  f32x4 acc[8][4]; ZERO_ACC8(acc);
  gemm256<DD>(A, W1, m0, n0, smem, acc);
  const int rb = m0 + wm*128 + lq*4;
  const int cb = n0 + wn*64 + lr;
#pragma unroll
  for (int nf=0;nf<4;++nf){
    const float bias = b1[cb + nf*16];
#pragma unroll
    for (int mf=0;mf<8;++mf)
#pragma unroll
      for (int rr=0;rr<4;++rr){
        float v = acc[mf][nf][rr] + bias;
        v = v > 0.f ? v : 0.f;
        Hout[(size_t)(rb + mf*16 + rr)*HH + (cb + nf*16)] = f2bf(v);
      }
  }
}

// ---- CMS level GEMM2: out += H @ w2^T + b2 (fp32 master + bf16 shadow). N=512, K=1024
__global__ __launch_bounds__(512, 2) void k_gemm_res(const int* __restrict__ gs, int freq,
     const short* __restrict__ Hb, const short* __restrict__ W2, const float* __restrict__ b2,
     float* __restrict__ outf, short* __restrict__ outb)
{
  if (gs[0] % freq) return;
  __shared__ __align__(16) short smem[65536];
  const int tid = threadIdx.x, wave = tid>>6, lane = tid&63;
  const int wm = wave>>2, wn = wave&3, lr = lane&15, lq = lane>>4;
  int2 r = xcd_remap(2, 512);
  const int m0 = r.x*256, n0 = r.y*256;
  f32x4 acc[8][4]; ZERO_ACC8(acc);
  gemm256<HH>(Hb, W2, m0, n0, smem, acc);
  const int rb = m0 + wm*128 + lq*4;
  const int cb = n0 + wn*64 + lr;
#pragma unroll
  for (int nf=0;nf<4;++nf){
    const float bias = b2[cb + nf*16];
#pragma unroll
    for (int mf=0;mf<8;++mf)
#pragma unroll
      for (int rr=0;rr<4;++rr){
        size_t off = (size_t)(rb + mf*16 + rr)*DD + (cb + nf*16);
        float v = acc[mf][nf][rr] + bias + outf[off];
        outf[off] = v;
        outb[off] = f2bf(v);
      }
  }
}

// ---- gates fused with gate-out: block handles one (j, n-tile); per-row dot
// with the 3 g_out_w rows, reduced in LDS, stored as NON-ATOMIC partials
// pacc[12][65536][3]; k_gatefin sums the 12 slices.
__global__ __launch_bounds__(512, 2) void k_gates(const short* __restrict__ A, const short* __restrict__ WG,
     const float* __restrict__ bm, const float* __restrict__ bs, const float* __restrict__ bg,
     const float* __restrict__ gow, float* __restrict__ pacc)
{
  __shared__ __align__(16) short smem[65536];
  __shared__ float sred[768];
  const int tid = threadIdx.x, wave = tid>>6, lane = tid&63;
  const int wm = wave>>2, wn = wave&3, lr = lane&15, lq = lane>>4;
  int2 r = xcd_remap(12, 3072);
  const int m0 = r.x*256, xj = r.y;
  const int j = xj >> 2, nb = xj & 3;
  const int n0 = nb*256;
  const int cb = n0 + wn*64 + lr;
  const float* bj = (j==0) ? bm : ((j==1) ? bs : bg);
  float gw0[4], gw1[4], gw2[4], bias[4];
#pragma unroll
  for (int nf=0;nf<4;++nf){
    gw0[nf]  = gow[cb + nf*16];
    gw1[nf]  = gow[1024 + cb + nf*16];
    gw2[nf]  = gow[2048 + cb + nf*16];
    bias[nf] = bj[cb + nf*16];
  }
  for (int i=tid;i<768;i+=512) sred[i]=0.f;
  f32x4 acc[8][4]; ZERO_ACC8(acc);
  gemm256<DD>(A, WG + (size_t)j*HH*DD, m0, n0, smem, acc);
  __syncthreads();
#pragma unroll
  for (int mf=0;mf<8;++mf)
#pragma unroll
    for (int rr=0;rr<4;++rr){
      float s0=0.f, s1=0.f, s2=0.f;
#pragma unroll
      for (int nf=0;nf<4;++nf){
        float v = sigm(acc[mf][nf][rr] + bias[nf]);
        s0 += v*gw0[nf]; s1 += v*gw1[nf]; s2 += v*gw2[nf];
      }
      s0 = rowsum16(s0); s1 = rowsum16(s1); s2 = rowsum16(s2);
      if (lr == 0){
        int lrow = wm*128 + mf*16 + lq*4 + rr;
        atomicAdd(&sred[lrow], s0);          // LDS-scope atomics (4 waves/row)
        atomicAdd(&sred[256+lrow], s1);
        atomicAdd(&sred[512+lrow], s2);
      }
    }
  __syncthreads();
  if (tid < 256){
    float* dst = &pacc[((size_t)xj*NB + m0 + tid)*3];
    dst[0] = sred[tid];
    dst[1] = sred[256+tid];
    dst[2] = sred[512+tid];
  }
}

// ---- slow/fast as one N=1024 GEMM (W = [W_slow; W_fast] contiguous), K=512
__global__ __launch_bounds__(512, 2) void k_slowfast(const short* __restrict__ A,
     const short* __restrict__ WSF,
     short* __restrict__ SB, short* __restrict__ FB, float* __restrict__ f2sum)
{
  __shared__ __align__(16) short smem[65536];
  __shared__ float f2red[256];
  const int tid = threadIdx.x, wave = tid>>6, lane = tid&63;
  const int wm = wave>>2, wn = wave&3, lr = lane&15, lq = lane>>4;
  int2 r = xcd_remap(4, 1024);
  const int m0 = r.x*256, n0 = r.y*256;
  const bool isfast = (n0 >= 512);
  if (isfast){
    for (int i=tid;i<256;i+=512) f2red[i]=0.f;
    __syncthreads();
  }
  f32x4 acc[8][4]; ZERO_ACC8(acc);
  gemm256<DD>(A, WSF, m0, n0, smem, acc);
  const int rb = m0 + wm*128 + lq*4;
  const int cb = n0 + wn*64 + lr;
  if (!isfast){
#pragma unroll
    for (int nf=0;nf<4;++nf)
#pragma unroll
      for (int mf=0;mf<8;++mf)
#pragma unroll
        for (int rr=0;rr<4;++rr)
          SB[(size_t)(rb + mf*16 + rr)*DD + (cb + nf*16)] = f2bf(acc[mf][nf][rr]);
  } else {
#pragma unroll
    for (int nf=0;nf<4;++nf){
      float p = 0.f;
      const int fcol = cb + nf*16 - 512;
#pragma unroll
      for (int mf=0;mf<8;++mf)
#pragma unroll
        for (int rr=0;rr<4;++rr){
          float fv = acc[mf][nf][rr];
          FB[(size_t)(rb + mf*16 + rr)*DD + fcol] = f2bf(fv);
          p += fv*fv;
        }
      atomicAdd(&f2red[wn*64 + nf*16 + lr], p);
    }
    __syncthreads();
    if (tid < 256) atomicAdd(&f2sum[(n0-512) + tid], f2red[tid]);
  }
}

// ---- hebb = fast^T @ x_cms (TN GEMM via LDS transpose, split-K=16 over B)
__global__ __launch_bounds__(256) void k_hebb(const short* __restrict__ FB,
     const short* __restrict__ XB, float* __restrict__ hebb)
{
  __shared__ __align__(16) short sT[10240];
  const int tid = threadIdx.x, wave = tid>>6, lane = tid&63;
  const int o0 = blockIdx.x*128, d0 = blockIdx.y*128;
  const int bz = blockIdx.z;
  const int tr = tid>>3;
  const int tc = (tid&7)*16;
  const int wm=(wave>>1)*64, wn=(wave&1)*64;
  const int lr = lane & 15, lk = (lane>>4)*8;
  f32x4 acc[4][4];
#pragma unroll
  for (int zi=0;zi<4;++zi)
#pragma unroll
    for (int zj=0;zj<4;++zj) acc[zi][zj] = (f32x4){0.f,0.f,0.f,0.f};
  for (int bb=0; bb<4096; bb+=32){
    const int b0 = bz*4096 + bb;
    __syncthreads();
#pragma unroll
    for (int h=0; h<2; ++h){
      short8 v = *(const short8*)&FB[(size_t)(b0+tr)*DD + o0 + tc + h*8];
#pragma unroll
      for (int j=0;j<8;++j) sT[(tc+h*8+j)*40 + tr] = v[j];
      short8 u = *(const short8*)&XB[(size_t)(b0+tr)*DD + d0 + tc + h*8];
#pragma unroll
      for (int j=0;j<8;++j) sT[5120 + (tc+h*8+j)*40 + tr] = u[j];
    }
    __syncthreads();
    short8 af[4], bf[4];
#pragma unroll
    for (int i=0;i<4;++i) af[i] = *(const short8*)&sT[(wm + i*16 + lr)*40 + lk];
#pragma unroll
    for (int i=0;i<4;++i) bf[i] = *(const short8*)&sT[5120 + (wn + i*16 + lr)*40 + lk];
#pragma unroll
    for (int mi=0;mi<4;++mi)
#pragma unroll
      for (int ni=0;ni<4;++ni)
        acc[mi][ni] = __builtin_amdgcn_mfma_f32_16x16x32_bf16(af[mi], bf[ni], acc[mi][ni], 0,0,0);
  }
  const int rbase = o0 + wm + ((lane>>4)<<2);
  const int cbase = d0 + wn + (lane&15);
#pragma unroll
  for (int mi=0;mi<4;++mi)
#pragma unroll
    for (int ni=0;ni<4;++ni)
#pragma unroll
      for (int r=0;r<4;++r)
        atomicAdd(&hebb[(size_t)(rbase + mi*16 + r)*DD + (cbase + ni*16)], acc[mi][ni][r]);
}

// ---- finalize gates: sum 12 partial slices, sigmoid, stats
__global__ __launch_bounds__(256) void k_gatefin(const float* __restrict__ pacc,
     const float* __restrict__ gob,
     float* __restrict__ sensb, float* __restrict__ gateb, float* __restrict__ sacc)
{
  __shared__ float red[3][256];
  const int tid = threadIdx.x;
  const int row = blockIdx.x*256 + tid;
  float a0=0.f, a1=0.f, a2=0.f;
#pragma unroll
  for (int sidx=0; sidx<12; ++sidx){
    const float* p = &pacc[((size_t)sidx*NB + row)*3];
    a0 += p[0]; a1 += p[1]; a2 += p[2];
  }
  float m = sigm(a0 + gob[0]);
  float s = sigm(a1 + gob[1]);
  float g = sigm(a2 + gob[2]);
  sensb[row] = s; gateb[row] = g;
  red[0][tid]=m; red[1][tid]=s; red[2][tid]=g;
  __syncthreads();
  for (int off=128; off; off>>=1){
    if (tid < off){
      red[0][tid]+=red[0][tid+off];
      red[1][tid]+=red[1][tid+off];
      red[2][tid]+=red[2][tid+off];
    }
    __syncthreads();
  }
  if (tid < 3) atomicAdd(&sacc[tid], red[tid][0]);
}

// ---- combined/SiLU-beta/LayerNorm epilogue: one wave per row
__global__ __launch_bounds__(256) void k_ln(const short* __restrict__ SB, const short* __restrict__ FB,
     const float* __restrict__ gate, const float* __restrict__ sens,
     const float* __restrict__ gam, const float* __restrict__ bet, float* __restrict__ out)
{
  const int tid = threadIdx.x, wave = tid>>6, lane = tid&63;
  const int row = blockIdx.x*4 + wave;
  const float g = gate[row], s = sens[row];
  const float bcoef = 0.5f + 2.0f*s;
  const int c0 = lane*8;
  short8 sv = *(const short8*)&SB[(size_t)row*DD + c0];
  short8 fv = *(const short8*)&FB[(size_t)row*DD + c0];
  float a[8]; float sum = 0.f;
#pragma unroll
  for (int j=0;j<8;++j){
    float c = bf2f(sv[j]) + bf2f(fv[j])*g;
    float av = c * sigm(bcoef*c);
    a[j] = av; sum += av;
  }
  for (int off=32; off; off>>=1) sum += __shfl_down(sum, off);
  sum = __shfl(sum, 0);
  const float mu = sum * (1.f/512.f);
  float vs = 0.f;
#pragma unroll
  for (int j=0;j<8;++j){ float d=a[j]-mu; vs += d*d; }
  for (int off=32; off; off>>=1) vs += __shfl_down(vs, off);
  vs = __shfl(vs, 0);
  const float rstd = rsqrtf(vs*(1.f/512.f) + 1e-5f);
  f32x4 o0, o1;
#pragma unroll
  for (int j=0;j<4;++j) o0[j] = (a[j]-mu)*rstd*gam[c0+j] + bet[c0+j];
#pragma unroll
  for (int j=0;j<4;++j) o1[j] = (a[4+j]-mu)*rstd*gam[c0+4+j] + bet[c0+4+j];
  *(f32x4*)&out[(size_t)row*DD + c0]     = o0;
  *(f32x4*)&out[(size_t)row*DD + c0 + 4] = o1;
}

// ---- new_W_fast + stats
__global__ __launch_bounds__(256) void k_wfast(const float* __restrict__ hebb,
     const float* __restrict__ f2sum, const float* __restrict__ sacc,
     const float* __restrict__ Wf, float* __restrict__ outw, float* __restrict__ outstats)
{
  const int idx = blockIdx.x*256 + threadIdx.x;
  if (idx >= 262144) return;
  const float inv = 1.f/65536.f;
  const float rate = sacc[0] * inv * 0.1f;
  const int o = idx >> 9;
  float w = Wf[idx];
  float h = hebb[idx] * inv;
  float forget = f2sum[o] * inv * w;
  outw[idx] = w + tanhf(h - forget) * rate;
  if (idx < 3) outstats[idx] = sacc[idx] * inv;
}

// ---- merged weight casts (7 segments in one launch)
__global__ __launch_bounds__(256) void k_castall(
     const float* __restrict__ w1, const float* __restrict__ w2,
     const float* __restrict__ gmw, const float* __restrict__ gsw, const float* __restrict__ ggw,
     const float* __restrict__ wslow, const float* __restrict__ wfast,
     short* __restrict__ wcW1, short* __restrict__ wcW2, short* __restrict__ wcG,
     short* __restrict__ wcWSF)
{
  const int b = blockIdx.x, t = threadIdx.x;
  const float* src; short* dst; int off;
  if      (b < 6144)  { src=w1;    dst=wcW1;           off=b; }
  else if (b < 12288) { src=w2;    dst=wcW2;           off=b-6144; }
  else if (b < 14336) { src=gmw;   dst=wcG;            off=b-12288; }
  else if (b < 16384) { src=gsw;   dst=wcG+524288;     off=b-14336; }
  else if (b < 18432) { src=ggw;   dst=wcG+1048576;    off=b-16384; }
  else if (b < 19456) { src=wslow; dst=wcWSF;          off=b-18432; }
  else                { src=wfast; dst=wcWSF+262144;   off=b-19456; }
  const int i = off*256 + t;
  dst[i] = f2bf(src[i]);
}

__global__ __launch_bounds__(256) void k_castx(const float* __restrict__ x,
     float* __restrict__ outf, short* __restrict__ outb)
{
  int i = blockIdx.x*256 + threadIdx.x;
  f32x4 v = *(const f32x4*)&x[(size_t)i*4];
  *(f32x4*)&outf[(size_t)i*4] = v;
  short4v b;
#pragma unroll
  for (int j=0;j<4;++j) b[j] = f2bf(v[j]);
  *(short4v*)&outb[(size_t)i*4] = b;
}

extern "C" void kernel_launch(void* const* d_in, const int* in_sizes, int n_in,
                              void* d_out, int out_size, void* d_ws, size_t ws_size,
                              hipStream_t stream)
{
  const float* x    = (const float*)d_in[0];
  const int*   gs   = (const int*)d_in[1];
  const float* w1   = (const float*)d_in[2];
  const float* b1   = (const float*)d_in[3];
  const float* w2   = (const float*)d_in[4];
  const float* b2   = (const float*)d_in[5];
  const float* gmw  = (const float*)d_in[6];
  const float* gmb  = (const float*)d_in[7];
  const float* gsw  = (const float*)d_in[8];
  const float* gsb  = (const float*)d_in[9];
  const float* ggw  = (const float*)d_in[10];
  const float* ggb  = (const float*)d_in[11];
  const float* gow  = (const float*)d_in[12];
  const float* gob  = (const float*)d_in[13];
  const float* wslow= (const float*)d_in[14];
  const float* wfast= (const float*)d_in[15];
  const float* gam  = (const float*)d_in[16];
  const float* bet  = (const float*)d_in[17];

  char* ws = (char*)d_ws;
  float* outf  = (float*)(ws + 0);            // fp32 x_cms master (dead after CMS)
  short* outb  = (short*)(ws + 134217728);    // x_cms bf16
  short* hbuf  = (short*)(ws + 201326592);    // H bf16 (CMS); pacc overlays later
  short* wcW1  = (short*)(ws + 335544320);
  short* wcW2  = (short*)(ws + 338690048);
  short* wcG   = (short*)(ws + 341835776);
  short* wcWSF = (short*)(ws + 344981504);    // [W_slow;W_fast] = [1024][512] bf16
  float* hebb  = (float*)(ws + 346030080);
  float* f2sum = (float*)(ws + 347078656);
  float* sacc  = (float*)(ws + 347080704);
  float* sensb = (float*)(ws + 347080960);
  float* gateb = (float*)(ws + 347343104);
  float* pacc  = (float*)(ws + 201326592);    // overlays hbuf (dead after CMS)
  short* slowb = (short*)(ws + 0);            // overlays outf (dead after CMS)
  short* fastb = (short*)(ws + 67108864);

  float* o_ln = (float*)d_out;
  float* o_wf = o_ln + (size_t)NB*DD;
  float* o_st = o_wf + 262144;

  hipMemsetAsync(hebb, 0, 1048576, stream);
  hipMemsetAsync(f2sum, 0, 2048, stream);
  hipMemsetAsync(sacc, 0, 256, stream);

  k_castall<<<dim3(20480),256,0,stream>>>(w1, w2, gmw, gsw, ggw, wslow, wfast,
                                          wcW1, wcW2, wcG, wcWSF);
  k_castx<<<dim3(32768),256,0,stream>>>(x, outf, outb);

  const int freqs[3] = {1,4,16};
  for (int lv=0; lv<3; ++lv){
    k_gemm_h  <<<dim3(4,256),512,0,stream>>>(gs, freqs[lv], outb, wcW1 + (size_t)lv*524288, b1 + lv*HH, hbuf);
    k_gemm_res<<<dim3(2,256),512,0,stream>>>(gs, freqs[lv], hbuf, wcW2 + (size_t)lv*524288, b2 + lv*DD, outf, outb);
  }

  k_gates   <<<dim3(12,256),512,0,stream>>>(outb, wcG, gmb, gsb, ggb, gow, pacc);
  k_gatefin <<<dim3(256),256,0,stream>>>(pacc, gob, sensb, gateb, sacc);
  k_slowfast<<<dim3(4,256),512,0,stream>>>(outb, wcWSF, slowb, fastb, f2sum);
  k_hebb    <<<dim3(4,4,16),256,0,stream>>>(fastb, outb, hebb);
  k_ln      <<<dim3(16384),256,0,stream>>>(slowb, fastb, gateb, sensb, gam, bet, o_ln);
  k_wfast   <<<dim3(1024),256,0,stream>>>(hebb, f2sum, sacc, wfast, o_wf, o_st);
}